// Round 3
// 205.950 us; speedup vs baseline: 1.0325x; 1.0325x over previous
//
#include <hip/hip_runtime.h>
#include <hip/hip_bf16.h>
#include <stdint.h>

typedef unsigned short u16;
typedef __bf16 bf16x8 __attribute__((ext_vector_type(8)));
typedef float f32x4 __attribute__((ext_vector_type(4)));
typedef float f32x16 __attribute__((ext_vector_type(16)));

__device__ __forceinline__ u16 f2bf(float f) {
    union { float f; unsigned u; } x; x.f = f;
    unsigned u = x.u;
    u += 0x7FFFu + ((u >> 16) & 1u);   // round-to-nearest-even
    return (u16)(u >> 16);
}
__device__ __forceinline__ float bf2f(u16 h) {
    union { unsigned u; float f; } x; x.u = ((unsigned)h) << 16; return x.f;
}

// async global->LDS, 16B per lane; LDS dest is wave-uniform base + lane*16.
typedef __attribute__((address_space(1))) void gvoid;
typedef __attribute__((address_space(3))) void lvoid;
__device__ __forceinline__ void gl2lds16(const void* g, void* l) {
    __builtin_amdgcn_global_load_lds((gvoid*)g, (lvoid*)l, 16, 0, 0);
}

// ---------------------------------------------------------------------------
// Merged prep: blocks [0,2048): cast x -> bf16; [2048,2816): castT Wqkv;
// [2816,3072): castT Wproj.
// ---------------------------------------------------------------------------
__global__ __launch_bounds__(256) void prep_kernel(
    const float* __restrict__ x, u16* __restrict__ xb,
    const float* __restrict__ Wqkv, u16* __restrict__ wqkvT,
    const float* __restrict__ Wproj, u16* __restrict__ wprojT)
{
    __shared__ u16 tile[64][65];
    const int blk = blockIdx.x;
    const int tid = threadIdx.x;

    if (blk < 2048) {
        const size_t i = ((size_t)blk * 256 + tid) * 8;
        float4 a = *(const float4*)(x + i);
        float4 b = *(const float4*)(x + i + 4);
        ushort4 oa, ob;
        oa.x = f2bf(a.x); oa.y = f2bf(a.y); oa.z = f2bf(a.z); oa.w = f2bf(a.w);
        ob.x = f2bf(b.x); ob.y = f2bf(b.y); ob.z = f2bf(b.z); ob.w = f2bf(b.w);
        *(ushort4*)(xb + i) = oa;
        *(ushort4*)(xb + i + 4) = ob;
        return;
    }
    const float* in; u16* out; int rows, cols, bx, by;
    if (blk < 2816) { int t = blk - 2048; in = Wqkv;  out = wqkvT;  rows = 1024; cols = 3072; bx = t % 48; by = t / 48; }
    else            { int t = blk - 2816; in = Wproj; out = wprojT; rows = 1024; cols = 1024; bx = t % 16; by = t / 16; }
#pragma unroll
    for (int i = 0; i < 16; i++) {
        int e = i * 256 + tid;
        int r = e >> 6, c = e & 63;
        tile[r][c] = f2bf(in[(size_t)(by * 64 + r) * cols + bx * 64 + c]);
    }
    __syncthreads();
#pragma unroll
    for (int i = 0; i < 16; i++) {
        int e = i * 256 + tid;
        int r = e >> 6, c = e & 63;
        out[(size_t)(bx * 64 + r) * rows + by * 64 + c] = tile[c][r];
    }
}

// ---------------------------------------------------------------------------
// QKV GEMM v4 (unchanged): gl2lds K-loop + LDS-repacked epilogue.
// ---------------------------------------------------------------------------
__global__ __launch_bounds__(256) void gemm_qkv(
    const u16* __restrict__ A, const u16* __restrict__ Bt,
    const float* __restrict__ bias,
    u16* __restrict__ q, u16* __restrict__ ko, u16* __restrict__ vt)
{
    constexpr int K = 1024;
    __shared__ __align__(16) u16 smem[128 * 132];
    u16* sA = smem;
    u16* sB = smem + 8192;
    const int tid = threadIdx.x;
    const int wave = tid >> 6, lane = tid & 63;
    const int quad = lane >> 4, l16 = lane & 15;
    const int wm = (wave >> 1) * 64, wn = (wave & 1) * 64;
    const int m0 = blockIdx.y * 128, n0 = blockIdx.x * 128;
    const int srow = lane >> 3;
    const int scol = (lane & 7) * 8;

    f32x4 acc[4][4];
#pragma unroll
    for (int i = 0; i < 4; i++)
#pragma unroll
        for (int j = 0; j < 4; j++)
#pragma unroll
            for (int r = 0; r < 4; r++) acc[i][j][r] = 0.f;

    for (int kt = 0; kt < K; kt += 64) {
        __syncthreads();
#pragma unroll
        for (int t = 0; t < 4; t++) {
            int rb = wave * 32 + t * 8;
            gl2lds16(A  + (size_t)(m0 + rb + srow) * K + kt + scol, &sA[rb * 64]);
            gl2lds16(Bt + (size_t)(n0 + rb + srow) * K + kt + scol, &sB[rb * 64]);
        }
        __syncthreads();
#pragma unroll
        for (int kk = 0; kk < 64; kk += 32) {
            bf16x8 af[4], bfr[4];
#pragma unroll
            for (int t = 0; t < 4; t++) {
                af[t]  = *(const bf16x8*)&sA[(wm + t * 16 + l16) * 64 + kk + quad * 8];
                bfr[t] = *(const bf16x8*)&sB[(wn + t * 16 + l16) * 64 + kk + quad * 8];
            }
#pragma unroll
            for (int i = 0; i < 4; i++)
#pragma unroll
                for (int j = 0; j < 4; j++)
                    acc[i][j] = __builtin_amdgcn_mfma_f32_16x16x32_bf16(
                        af[i], bfr[j], acc[i][j], 0, 0, 0);
        }
    }

    const float QSCALE = 0.18033688011112042f;  // 0.125 * log2(e)
    const float sc = (n0 < 1024) ? QSCALE : 1.0f;
    __syncthreads();
#pragma unroll
    for (int i = 0; i < 4; i++) {
#pragma unroll
        for (int j = 0; j < 4; j++) {
            float bv = bias[n0 + wn + j * 16 + l16];
#pragma unroll
            for (int r = 0; r < 4; r++) {
                float v = (acc[i][j][r] + bv) * sc;
                smem[(wm + i * 16 + quad * 4 + r) * 132 + wn + j * 16 + l16] = f2bf(v);
            }
        }
    }
    __syncthreads();

    if (n0 < 2048) {
        u16* dst = (n0 < 1024) ? q : ko;
#pragma unroll
        for (int it = 0; it < 8; it++) {
            int c = it * 256 + tid;
            int m_l = c >> 4;
            int n8 = (c & 15) * 8;
            uint4 w = *(const uint4*)&smem[m_l * 132 + n8];
            int n = n0 + n8;
            int h = (n & 1023) >> 6, d = n & 63;
            int m = m0 + m_l;
            int b = m >> 11, t = m & 2047;
            *(uint4*)(dst + ((size_t)(b * 16 + h) * 2048 + t) * 64 + d) = w;
        }
    } else {
        int nv = n0 - 2048;
        int n_l = tid & 127, mh = tid >> 7;
        int hh = (nv >> 6) + (n_l >> 6);
        int d = n_l & 63;
        int bb = m0 >> 11, t0 = m0 & 2047;
        u16* vrow = vt + ((size_t)(bb * 16 + hh) * 64 + d) * 2048 + t0 + mh * 64;
#pragma unroll
        for (int it = 0; it < 8; it++) {
            int tch = mh * 64 + it * 8;
            union { u16 s[8]; uint4 w; } pk;
#pragma unroll
            for (int i = 0; i < 8; i++)
                pk.s[i] = smem[(tch + i) * 132 + n_l];
            *(uint4*)(vrow + it * 8) = pk.w;
        }
    }
}

// ---------------------------------------------------------------------------
// Flash attention v10: swapped 32x32 QK^T (S^T = mfma(K,Q)); P entirely in
// registers. Pairing proof: (a) A-map==B-map (empirically proven: rounds 0/1
// had SMALL error, so QK^T -- which relies only on (a) -- was correct);
// (b) C/D reg->row = (r&3)+8*(r>>2)+4*hi (HW-verified m74/m101). Under
// (a)+(b), placing P[krow f(hi,j)] in A slot (hi,j) and V[row f(hi,j)] in
// B slot (hi,j) with f = 4*hi+(j&3)+8*(j>>2) (+16*ks2+32*rb) telescopes to
// the exact sum for ANY shared hw k-map. Round-1's residual bug was
// v_cvt_pk_bf16_f32 operand order (only remaining suspect) -> replaced with
// explicit f2bf bit-packing (order-proof). lsum sums pre-round floats
// (~4e-5 relative inconsistency, negligible).
// ---------------------------------------------------------------------------
__global__ __launch_bounds__(256, 4) void attn_kernel(
    const u16* __restrict__ q, const u16* __restrict__ ko,
    const u16* __restrict__ vt,
    u16* __restrict__ op0, u16* __restrict__ op1,
    float* __restrict__ lp0, float* __restrict__ lp1)
{
    __shared__ __align__(16) u16 sK[2][64 * 72];   // [n][d], pitch 72
    __shared__ __align__(16) u16 sV[2][64 * 72];   // [d][n], pitch 72

    const int tid = threadIdx.x;
    const int wave = tid >> 6, lane = tid & 63;
    const int l31 = lane & 31, hi = lane >> 5;

    const int lid = blockIdx.x;
    const int xcd = lid & 7, idx = lid >> 3;     // idx 0..127
    const int h = xcd * 2 + (idx & 1);
    const int b = (idx >> 1) & 1;
    const int q0 = ((idx >> 2) & 15) * 128;
    const int khalf = idx >> 6;                  // 0 or 1
    const int kbase = khalf * 1024;
    const size_t bh = (size_t)(b * 16 + h);

    const u16* qp  = q  + bh * 2048 * 64;
    const u16* kp  = ko + bh * 2048 * 64;
    const u16* vtp = vt + bh * 64 * 2048;

    // Q fragments straight from global: B-operand of 32x32x16.
    // lane holds Q[q = q0+wave*32+l31][d = dstep*16 + hi*8 + 0..7]
    bf16x8 qf[4];
    {
        const u16* qrow = qp + (size_t)(q0 + wave * 32 + l31) * 64 + hi * 8;
#pragma unroll
        for (int d = 0; d < 4; d++)
            qf[d] = *(const bf16x8*)(qrow + d * 16);
    }

    const int sr0 = tid >> 3;          // 0..31
    const int sc0 = (tid & 7) * 8;
    const int sr1 = sr0 + 32;

    // prefetch tile 0 K/V of this half
    uint4 pk0 = *(const uint4*)(kp + (size_t)(kbase + sr0) * 64 + sc0);
    uint4 pk1 = *(const uint4*)(kp + (size_t)(kbase + sr1) * 64 + sc0);
    uint4 pv0 = *(const uint4*)(vtp + (size_t)sr0 * 2048 + kbase + sc0);
    uint4 pv1 = *(const uint4*)(vtp + (size_t)sr1 * 2048 + kbase + sc0);

    f32x16 accO[2];
#pragma unroll
    for (int d = 0; d < 2; d++)
#pragma unroll
        for (int r = 0; r < 16; r++) accO[d][r] = 0.f;
    float lsum = 0.f;

    for (int t = 0; t < 16; ++t) {
        const int cur = t & 1;
        u16* sKc = &sK[cur][0];
        u16* sVc = &sV[cur][0];
        // write staged tile t into buffer cur (last read of this buffer was
        // compute(t-2); two barriers separate -> safe)
        *(uint4*)&sKc[sr0 * 72 + sc0] = pk0;
        *(uint4*)&sKc[sr1 * 72 + sc0] = pk1;
        *(uint4*)&sVc[sr0 * 72 + sc0] = pv0;
        *(uint4*)&sVc[sr1 * 72 + sc0] = pv1;
        if (t < 15) {
            int nt = kbase + (t + 1) * 64;
            pk0 = *(const uint4*)(kp + (size_t)(nt + sr0) * 64 + sc0);
            pk1 = *(const uint4*)(kp + (size_t)(nt + sr1) * 64 + sc0);
            pv0 = *(const uint4*)(vtp + (size_t)sr0 * 2048 + nt + sc0);
            pv1 = *(const uint4*)(vtp + (size_t)sr1 * 2048 + nt + sc0);
        }
        __syncthreads();

#pragma unroll
        for (int rb = 0; rb < 2; rb++) {
            // S^T block: D = mfma(A=K, B=Q), lane holds
            // S^T[krow = (r&3)+8*(r>>2)+4*hi][q = l31] (rows rb*32..+31)
            f32x16 S;
#pragma unroll
            for (int r = 0; r < 16; r++) S[r] = 0.f;
            const u16* krd = &sKc[(rb * 32 + l31) * 72 + hi * 8];
#pragma unroll
            for (int d = 0; d < 4; d++) {
                bf16x8 kf = *(const bf16x8*)(krd + d * 16);
                S = __builtin_amdgcn_mfma_f32_32x32x16_bf16(kf, qf[d], S, 0, 0, 0);
            }
            // P = exp2(S); l accumulates pre-round floats (negligible skew).
            float e[16];
#pragma unroll
            for (int r = 0; r < 16; r++) {
                e[r] = __builtin_amdgcn_exp2f(S[r]);
                lsum += e[r];
            }
            // O += P @ V. A slot (hi,j) <- P[krow f], B slot (hi,j) <- V[row f],
            // f = rb*32 + ks2*16 + 4*hi + (j&3) + 8*(j>>2).
            // elem j of pa <-> S reg r = 8*ks2 + 4*(j>>2) + (j&3), i.e. regs
            // [8ks2..8ks2+7] in order; packed LOW=even reg via explicit bitops.
#pragma unroll
            for (int ks2 = 0; ks2 < 2; ks2++) {
                union { unsigned u[4]; bf16x8 v; } pa;
#pragma unroll
                for (int s = 0; s < 4; s++) {
                    unsigned lo = f2bf(e[ks2 * 8 + 2 * s]);
                    unsigned hh = f2bf(e[ks2 * 8 + 2 * s + 1]);
                    pa.u[s] = lo | (hh << 16);
                }
                const int nb = rb * 32 + ks2 * 16 + 4 * hi;
#pragma unroll
                for (int db = 0; db < 2; db++) {
                    const u16* vr = &sVc[(db * 32 + l31) * 72 + nb];
                    union { uint2 w[2]; bf16x8 v; } vf;
                    vf.w[0] = *(const uint2*)(vr);
                    vf.w[1] = *(const uint2*)(vr + 8);
                    accO[db] = __builtin_amdgcn_mfma_f32_32x32x16_bf16(pa.v, vf.v, accO[db], 0, 0, 0);
                }
            }
        }
        __syncthreads();
    }

    // epilogue: write unnormalized O (bf16) + l (fp32) for this half
    u16* op = khalf ? op1 : op0;
    float* lp = khalf ? lp1 : lp0;

    float ltot = lsum + __shfl_xor(lsum, 32, 64);
    int qq0 = q0 + wave * 32;
    if (hi == 0) lp[bh * 2048 + qq0 + l31] = ltot;

#pragma unroll
    for (int db = 0; db < 2; db++)
#pragma unroll
        for (int r = 0; r < 16; r++) {
            int tq = qq0 + (r & 3) + 8 * (r >> 2) + 4 * hi;
            size_t row = (size_t)b * 2048 + tq;
            op[row * 1024 + h * 64 + db * 32 + l31] = f2bf(accO[db][r]);
        }
}

// ---------------------------------------------------------------------------
// Combine: ob = (O0 + O1) / (l0 + l1); ob aliases op0 (same-element RMW safe).
// ---------------------------------------------------------------------------
__global__ __launch_bounds__(256) void combine_kernel(
    const u16* __restrict__ op0, const u16* __restrict__ op1,
    const float* __restrict__ lp0, const float* __restrict__ lp1,
    u16* __restrict__ ob)
{
    const size_t i = ((size_t)blockIdx.x * 256 + threadIdx.x) * 8;
    int m = (int)(i >> 10), e = (int)(i & 1023);
    int b = m >> 11, t = m & 2047, h = e >> 6;
    float inv = 1.f / (lp0[(size_t)(b * 16 + h) * 2048 + t] +
                       lp1[(size_t)(b * 16 + h) * 2048 + t]);
    union { uint4 w; u16 s[8]; } a, c, o;
    a.w = *(const uint4*)(op0 + i);
    c.w = *(const uint4*)(op1 + i);
#pragma unroll
    for (int k = 0; k < 8; k++)
        o.s[k] = f2bf((bf2f(a.s[k]) + bf2f(c.s[k])) * inv);
    *(uint4*)(ob + i) = o.w;
}

// ---------------------------------------------------------------------------
// Proj GEMM v4 (unchanged): 64m x 128n tiles, grid 512, XCD m-super-tile.
// ---------------------------------------------------------------------------
__global__ __launch_bounds__(256) void gemm_proj(
    const u16* __restrict__ A, const u16* __restrict__ Bt,
    const float* __restrict__ bias, float* __restrict__ out)
{
    constexpr int K = 1024;
    __shared__ __align__(16) u16 sA[64 * 64];
    __shared__ __align__(16) u16 sB[128 * 64];
    const int tid = threadIdx.x;
    const int wave = tid >> 6, lane = tid & 63;
    const int quad = lane >> 4, l16 = lane & 15;
    const int wm = (wave & 1) * 32, wn = (wave >> 1) * 64;

    const int lid = blockIdx.x;
    const int xcd = lid & 7, idx = lid >> 3;   // idx 0..63
    const int m0 = (xcd * 8 + (idx & 7)) * 64;
    const int n0 = (idx >> 3) * 128;

    const int srow = lane >> 3;
    const int scol = (lane & 7) * 8;

    f32x4 acc[2][4];
#pragma unroll
    for (int i = 0; i < 2; i++)
#pragma unroll
        for (int j = 0; j < 4; j++)
#pragma unroll
            for (int r = 0; r < 4; r++) acc[i][j][r] = 0.f;

    for (int kt = 0; kt < K; kt += 64) {
        __syncthreads();
#pragma unroll
        for (int t = 0; t < 2; t++) {
            int rb = wave * 16 + t * 8;
            gl2lds16(A + (size_t)(m0 + rb + srow) * K + kt + scol, &sA[rb * 64]);
        }
#pragma unroll
        for (int t = 0; t < 4; t++) {
            int rb = wave * 32 + t * 8;
            gl2lds16(Bt + (size_t)(n0 + rb + srow) * K + kt + scol, &sB[rb * 64]);
        }
        __syncthreads();
#pragma unroll
        for (int kk = 0; kk < 64; kk += 32) {
            bf16x8 af[2], bfr[4];
#pragma unroll
            for (int t = 0; t < 2; t++)
                af[t] = *(const bf16x8*)&sA[(wm + t * 16 + l16) * 64 + kk + quad * 8];
#pragma unroll
            for (int t = 0; t < 4; t++)
                bfr[t] = *(const bf16x8*)&sB[(wn + t * 16 + l16) * 64 + kk + quad * 8];
#pragma unroll
            for (int i = 0; i < 2; i++)
#pragma unroll
                for (int j = 0; j < 4; j++)
                    acc[i][j] = __builtin_amdgcn_mfma_f32_16x16x32_bf16(
                        af[i], bfr[j], acc[i][j], 0, 0, 0);
        }
    }

#pragma unroll
    for (int i = 0; i < 2; i++) {
#pragma unroll
        for (int j = 0; j < 4; j++) {
            int n = n0 + wn + j * 16 + l16;
            float bv = bias[n];
#pragma unroll
            for (int r = 0; r < 4; r++) {
                int m = m0 + wm + i * 16 + quad * 4 + r;
                out[(size_t)m * 1024 + n] = acc[i][j][r] + bv;
            }
        }
    }
}

// ---------------------------------------------------------------------------
extern "C" void kernel_launch(void* const* d_in, const int* in_sizes, int n_in,
                              void* d_out, int out_size, void* d_ws, size_t ws_size,
                              hipStream_t stream) {
    const float* x     = (const float*)d_in[0];
    const float* Wqkv  = (const float*)d_in[1];
    const float* bqkv  = (const float*)d_in[2];
    const float* Wproj = (const float*)d_in[3];
    const float* bproj = (const float*)d_in[4];
    float* out = (float*)d_out;
    char* ws = (char*)d_ws;

    u16* wqkvT  = (u16*)(ws);              // 6291456 B (dead after gemm_qkv)
    u16* wprojT = (u16*)(ws +  6291456);   // 2097152 B (live until gemm_proj)
    u16* xb     = (u16*)(ws +  8388608);   // 8388608 B (dead after gemm_qkv)
    u16* qb     = (u16*)(ws + 16777216);   // [B,H,N,D]
    u16* kb     = (u16*)(ws + 25165824);   // [B,H,N,D]
    u16* vtb    = (u16*)(ws + 33554432);   // [B,H,D,N]
    u16* ob     = (u16*)(ws + 41943040);   // [B,N,E]  (= op0, combined in place)

    // partial buffers reuse dead slots during attention:
    u16*   op0 = ob;                       // half-0 unnormalized O (bf16)
    u16*   op1 = xb;                       // half-1 unnormalized O (bf16)
    float* lp0 = (float*)wqkvT;            // 65536 floats = 256 KB
    float* lp1 = (float*)(ws + 262144);    // next 256 KB (still in wqkvT slot)

    prep_kernel<<<dim3(3072), 256, 0, stream>>>(x, xb, Wqkv, wqkvT, Wproj, wprojT);
    gemm_qkv<<<dim3(24, 32), 256, 0, stream>>>(xb, wqkvT, bqkv, qb, kb, vtb);
    attn_kernel<<<dim3(1024), 256, 0, stream>>>(qb, kb, vtb, op0, op1, lp0, lp1);
    combine_kernel<<<dim3(2048), 256, 0, stream>>>(op0, op1, lp0, lp1, ob);
    gemm_proj<<<dim3(512), 256, 0, stream>>>(ob, wprojT, bproj, out);
}

// Round 4
// 194.818 us; speedup vs baseline: 1.0915x; 1.0571x over previous
//
#include <hip/hip_runtime.h>
#include <hip/hip_bf16.h>
#include <stdint.h>

typedef unsigned short u16;
typedef __bf16 bf16x8 __attribute__((ext_vector_type(8)));
typedef float f32x4 __attribute__((ext_vector_type(4)));
typedef float f32x16 __attribute__((ext_vector_type(16)));

__device__ __forceinline__ u16 f2bf(float f) {
    union { float f; unsigned u; } x; x.f = f;
    unsigned u = x.u;
    u += 0x7FFFu + ((u >> 16) & 1u);   // round-to-nearest-even
    return (u16)(u >> 16);
}
__device__ __forceinline__ float bf2f(u16 h) {
    union { unsigned u; float f; } x; x.u = ((unsigned)h) << 16; return x.f;
}

// async global->LDS, 16B per lane; LDS dest is wave-uniform base + lane*16.
typedef __attribute__((address_space(1))) void gvoid;
typedef __attribute__((address_space(3))) void lvoid;
__device__ __forceinline__ void gl2lds16(const void* g, void* l) {
    __builtin_amdgcn_global_load_lds((gvoid*)g, (lvoid*)l, 16, 0, 0);
}

// ---------------------------------------------------------------------------
// Merged prep: blocks [0,2048): cast x -> bf16; [2048,2816): castT Wqkv;
// [2816,3072): castT Wproj.
// ---------------------------------------------------------------------------
__global__ __launch_bounds__(256) void prep_kernel(
    const float* __restrict__ x, u16* __restrict__ xb,
    const float* __restrict__ Wqkv, u16* __restrict__ wqkvT,
    const float* __restrict__ Wproj, u16* __restrict__ wprojT)
{
    __shared__ u16 tile[64][65];
    const int blk = blockIdx.x;
    const int tid = threadIdx.x;

    if (blk < 2048) {
        const size_t i = ((size_t)blk * 256 + tid) * 8;
        float4 a = *(const float4*)(x + i);
        float4 b = *(const float4*)(x + i + 4);
        ushort4 oa, ob;
        oa.x = f2bf(a.x); oa.y = f2bf(a.y); oa.z = f2bf(a.z); oa.w = f2bf(a.w);
        ob.x = f2bf(b.x); ob.y = f2bf(b.y); ob.z = f2bf(b.z); ob.w = f2bf(b.w);
        *(ushort4*)(xb + i) = oa;
        *(ushort4*)(xb + i + 4) = ob;
        return;
    }
    const float* in; u16* out; int rows, cols, bx, by;
    if (blk < 2816) { int t = blk - 2048; in = Wqkv;  out = wqkvT;  rows = 1024; cols = 3072; bx = t % 48; by = t / 48; }
    else            { int t = blk - 2816; in = Wproj; out = wprojT; rows = 1024; cols = 1024; bx = t % 16; by = t / 16; }
#pragma unroll
    for (int i = 0; i < 16; i++) {
        int e = i * 256 + tid;
        int r = e >> 6, c = e & 63;
        tile[r][c] = f2bf(in[(size_t)(by * 64 + r) * cols + bx * 64 + c]);
    }
    __syncthreads();
#pragma unroll
    for (int i = 0; i < 16; i++) {
        int e = i * 256 + tid;
        int r = e >> 6, c = e & 63;
        out[(size_t)(bx * 64 + r) * rows + by * 64 + c] = tile[c][r];
    }
}

// ---------------------------------------------------------------------------
// QKV GEMM v5: v4 + T2 XOR-swizzle on sA/sB (rule #21: gl2lds writes
// linearly, so swizzle = pre-swizzled GLOBAL source col + swizzled read
// slot). LDS slot (row, s) holds global col-slot (s ^ (row&7)); read of
// col-slot c from row r uses slot c ^ (r&7). Kills the 16-way ds_read_b128
// conflict ([row][64] tile: row stride = 32 dwords -> fixed-quad lanes all
// on same 4 banks). After swizzle: 2 lanes/bank (free, m136).
// ---------------------------------------------------------------------------
__global__ __launch_bounds__(256) void gemm_qkv(
    const u16* __restrict__ A, const u16* __restrict__ Bt,
    const float* __restrict__ bias,
    u16* __restrict__ q, u16* __restrict__ ko, u16* __restrict__ vt)
{
    constexpr int K = 1024;
    __shared__ __align__(16) u16 smem[128 * 132];
    u16* sA = smem;
    u16* sB = smem + 8192;
    const int tid = threadIdx.x;
    const int wave = tid >> 6, lane = tid & 63;
    const int quad = lane >> 4, l16 = lane & 15;
    const int wm = (wave >> 1) * 64, wn = (wave & 1) * 64;
    const int m0 = blockIdx.y * 128, n0 = blockIdx.x * 128;
    const int srow = lane >> 3;                    // 0..7
    const int scolz = ((lane & 7) ^ srow) * 8;     // swizzled SOURCE col

    f32x4 acc[4][4];
#pragma unroll
    for (int i = 0; i < 4; i++)
#pragma unroll
        for (int j = 0; j < 4; j++)
#pragma unroll
            for (int r = 0; r < 4; r++) acc[i][j][r] = 0.f;

    for (int kt = 0; kt < K; kt += 64) {
        __syncthreads();
#pragma unroll
        for (int t = 0; t < 4; t++) {
            int rb = wave * 32 + t * 8;
            gl2lds16(A  + (size_t)(m0 + rb + srow) * K + kt + scolz, &sA[rb * 64]);
            gl2lds16(Bt + (size_t)(n0 + rb + srow) * K + kt + scolz, &sB[rb * 64]);
        }
        __syncthreads();
#pragma unroll
        for (int kk = 0; kk < 64; kk += 32) {
            bf16x8 af[4], bfr[4];
#pragma unroll
            for (int t = 0; t < 4; t++) {
                int sl = (((kk >> 3) + quad) ^ (l16 & 7)) * 8;   // swizzled slot
                af[t]  = *(const bf16x8*)&sA[(wm + t * 16 + l16) * 64 + sl];
                bfr[t] = *(const bf16x8*)&sB[(wn + t * 16 + l16) * 64 + sl];
            }
#pragma unroll
            for (int i = 0; i < 4; i++)
#pragma unroll
                for (int j = 0; j < 4; j++)
                    acc[i][j] = __builtin_amdgcn_mfma_f32_16x16x32_bf16(
                        af[i], bfr[j], acc[i][j], 0, 0, 0);
        }
    }

    const float QSCALE = 0.18033688011112042f;  // 0.125 * log2(e)
    const float sc = (n0 < 1024) ? QSCALE : 1.0f;
    __syncthreads();
#pragma unroll
    for (int i = 0; i < 4; i++) {
#pragma unroll
        for (int j = 0; j < 4; j++) {
            float bv = bias[n0 + wn + j * 16 + l16];
#pragma unroll
            for (int r = 0; r < 4; r++) {
                float v = (acc[i][j][r] + bv) * sc;
                smem[(wm + i * 16 + quad * 4 + r) * 132 + wn + j * 16 + l16] = f2bf(v);
            }
        }
    }
    __syncthreads();

    if (n0 < 2048) {
        u16* dst = (n0 < 1024) ? q : ko;
#pragma unroll
        for (int it = 0; it < 8; it++) {
            int c = it * 256 + tid;
            int m_l = c >> 4;
            int n8 = (c & 15) * 8;
            uint4 w = *(const uint4*)&smem[m_l * 132 + n8];
            int n = n0 + n8;
            int h = (n & 1023) >> 6, d = n & 63;
            int m = m0 + m_l;
            int b = m >> 11, t = m & 2047;
            *(uint4*)(dst + ((size_t)(b * 16 + h) * 2048 + t) * 64 + d) = w;
        }
    } else {
        int nv = n0 - 2048;
        int n_l = tid & 127, mh = tid >> 7;
        int hh = (nv >> 6) + (n_l >> 6);
        int d = n_l & 63;
        int bb = m0 >> 11, t0 = m0 & 2047;
        u16* vrow = vt + ((size_t)(bb * 16 + hh) * 64 + d) * 2048 + t0 + mh * 64;
#pragma unroll
        for (int it = 0; it < 8; it++) {
            int tch = mh * 64 + it * 8;
            union { u16 s[8]; uint4 w; } pk;
#pragma unroll
            for (int i = 0; i < 8; i++)
                pk.s[i] = smem[(tch + i) * 132 + n_l];
            *(uint4*)(vrow + it * 8) = pk.w;
        }
    }
}

// ---------------------------------------------------------------------------
// Flash attention v10 (frozen, passing): swapped 32x32 QK^T, in-register P
// via order-proof f2bf bit-packing, matched V b64 reads.
// ---------------------------------------------------------------------------
__global__ __launch_bounds__(256, 4) void attn_kernel(
    const u16* __restrict__ q, const u16* __restrict__ ko,
    const u16* __restrict__ vt,
    u16* __restrict__ op0, u16* __restrict__ op1,
    float* __restrict__ lp0, float* __restrict__ lp1)
{
    __shared__ __align__(16) u16 sK[2][64 * 72];   // [n][d], pitch 72
    __shared__ __align__(16) u16 sV[2][64 * 72];   // [d][n], pitch 72

    const int tid = threadIdx.x;
    const int wave = tid >> 6, lane = tid & 63;
    const int l31 = lane & 31, hi = lane >> 5;

    const int lid = blockIdx.x;
    const int xcd = lid & 7, idx = lid >> 3;     // idx 0..127
    const int h = xcd * 2 + (idx & 1);
    const int b = (idx >> 1) & 1;
    const int q0 = ((idx >> 2) & 15) * 128;
    const int khalf = idx >> 6;                  // 0 or 1
    const int kbase = khalf * 1024;
    const size_t bh = (size_t)(b * 16 + h);

    const u16* qp  = q  + bh * 2048 * 64;
    const u16* kp  = ko + bh * 2048 * 64;
    const u16* vtp = vt + bh * 64 * 2048;

    // Q fragments straight from global: B-operand of 32x32x16.
    bf16x8 qf[4];
    {
        const u16* qrow = qp + (size_t)(q0 + wave * 32 + l31) * 64 + hi * 8;
#pragma unroll
        for (int d = 0; d < 4; d++)
            qf[d] = *(const bf16x8*)(qrow + d * 16);
    }

    const int sr0 = tid >> 3;          // 0..31
    const int sc0 = (tid & 7) * 8;
    const int sr1 = sr0 + 32;

    // prefetch tile 0 K/V of this half
    uint4 pk0 = *(const uint4*)(kp + (size_t)(kbase + sr0) * 64 + sc0);
    uint4 pk1 = *(const uint4*)(kp + (size_t)(kbase + sr1) * 64 + sc0);
    uint4 pv0 = *(const uint4*)(vtp + (size_t)sr0 * 2048 + kbase + sc0);
    uint4 pv1 = *(const uint4*)(vtp + (size_t)sr1 * 2048 + kbase + sc0);

    f32x16 accO[2];
#pragma unroll
    for (int d = 0; d < 2; d++)
#pragma unroll
        for (int r = 0; r < 16; r++) accO[d][r] = 0.f;
    float lsum = 0.f;

    for (int t = 0; t < 16; ++t) {
        const int cur = t & 1;
        u16* sKc = &sK[cur][0];
        u16* sVc = &sV[cur][0];
        *(uint4*)&sKc[sr0 * 72 + sc0] = pk0;
        *(uint4*)&sKc[sr1 * 72 + sc0] = pk1;
        *(uint4*)&sVc[sr0 * 72 + sc0] = pv0;
        *(uint4*)&sVc[sr1 * 72 + sc0] = pv1;
        if (t < 15) {
            int nt = kbase + (t + 1) * 64;
            pk0 = *(const uint4*)(kp + (size_t)(nt + sr0) * 64 + sc0);
            pk1 = *(const uint4*)(kp + (size_t)(nt + sr1) * 64 + sc0);
            pv0 = *(const uint4*)(vtp + (size_t)sr0 * 2048 + nt + sc0);
            pv1 = *(const uint4*)(vtp + (size_t)sr1 * 2048 + nt + sc0);
        }
        __syncthreads();

#pragma unroll
        for (int rb = 0; rb < 2; rb++) {
            // S^T block: D = mfma(A=K, B=Q), lane holds
            // S^T[krow = (r&3)+8*(r>>2)+4*hi][q = l31] (rows rb*32..+31)
            f32x16 S;
#pragma unroll
            for (int r = 0; r < 16; r++) S[r] = 0.f;
            const u16* krd = &sKc[(rb * 32 + l31) * 72 + hi * 8];
#pragma unroll
            for (int d = 0; d < 4; d++) {
                bf16x8 kf = *(const bf16x8*)(krd + d * 16);
                S = __builtin_amdgcn_mfma_f32_32x32x16_bf16(kf, qf[d], S, 0, 0, 0);
            }
            float e[16];
#pragma unroll
            for (int r = 0; r < 16; r++) {
                e[r] = __builtin_amdgcn_exp2f(S[r]);
                lsum += e[r];
            }
            // O += P @ V. A slot (hi,j) <- P[krow f], B slot (hi,j) <- V[row f],
            // f = rb*32 + ks2*16 + 4*hi + (j&3) + 8*(j>>2).
#pragma unroll
            for (int ks2 = 0; ks2 < 2; ks2++) {
                union { unsigned u[4]; bf16x8 v; } pa;
#pragma unroll
                for (int s = 0; s < 4; s++) {
                    unsigned lo = f2bf(e[ks2 * 8 + 2 * s]);
                    unsigned hh = f2bf(e[ks2 * 8 + 2 * s + 1]);
                    pa.u[s] = lo | (hh << 16);
                }
                const int nb = rb * 32 + ks2 * 16 + 4 * hi;
#pragma unroll
                for (int db = 0; db < 2; db++) {
                    const u16* vr = &sVc[(db * 32 + l31) * 72 + nb];
                    union { uint2 w[2]; bf16x8 v; } vf;
                    vf.w[0] = *(const uint2*)(vr);
                    vf.w[1] = *(const uint2*)(vr + 8);
                    accO[db] = __builtin_amdgcn_mfma_f32_32x32x16_bf16(pa.v, vf.v, accO[db], 0, 0, 0);
                }
            }
        }
        __syncthreads();
    }

    // epilogue: write unnormalized O (bf16) + l (fp32) for this half
    u16* op = khalf ? op1 : op0;
    float* lp = khalf ? lp1 : lp0;

    float ltot = lsum + __shfl_xor(lsum, 32, 64);
    int qq0 = q0 + wave * 32;
    if (hi == 0) lp[bh * 2048 + qq0 + l31] = ltot;

#pragma unroll
    for (int db = 0; db < 2; db++)
#pragma unroll
        for (int r = 0; r < 16; r++) {
            int tq = qq0 + (r & 3) + 8 * (r >> 2) + 4 * hi;
            size_t row = (size_t)b * 2048 + tq;
            op[row * 1024 + h * 64 + db * 32 + l31] = f2bf(accO[db][r]);
        }
}

// ---------------------------------------------------------------------------
// Combine: ob = (O0 + O1) / (l0 + l1); ob aliases op0 (same-element RMW safe).
// ---------------------------------------------------------------------------
__global__ __launch_bounds__(256) void combine_kernel(
    const u16* __restrict__ op0, const u16* __restrict__ op1,
    const float* __restrict__ lp0, const float* __restrict__ lp1,
    u16* __restrict__ ob)
{
    const size_t i = ((size_t)blockIdx.x * 256 + threadIdx.x) * 8;
    int m = (int)(i >> 10), e = (int)(i & 1023);
    int b = m >> 11, t = m & 2047, h = e >> 6;
    float inv = 1.f / (lp0[(size_t)(b * 16 + h) * 2048 + t] +
                       lp1[(size_t)(b * 16 + h) * 2048 + t]);
    union { uint4 w; u16 s[8]; } a, c, o;
    a.w = *(const uint4*)(op0 + i);
    c.w = *(const uint4*)(op1 + i);
#pragma unroll
    for (int k = 0; k < 8; k++)
        o.s[k] = f2bf((bf2f(a.s[k]) + bf2f(c.s[k])) * inv);
    *(uint4*)(ob + i) = o.w;
}

// ---------------------------------------------------------------------------
// Proj GEMM v5: v4 + the same T2 XOR-swizzle (pre-swizzled gl2lds source +
// swizzled read slot) on sA/sB.
// ---------------------------------------------------------------------------
__global__ __launch_bounds__(256) void gemm_proj(
    const u16* __restrict__ A, const u16* __restrict__ Bt,
    const float* __restrict__ bias, float* __restrict__ out)
{
    constexpr int K = 1024;
    __shared__ __align__(16) u16 sA[64 * 64];
    __shared__ __align__(16) u16 sB[128 * 64];
    const int tid = threadIdx.x;
    const int wave = tid >> 6, lane = tid & 63;
    const int quad = lane >> 4, l16 = lane & 15;
    const int wm = (wave & 1) * 32, wn = (wave >> 1) * 64;

    const int lid = blockIdx.x;
    const int xcd = lid & 7, idx = lid >> 3;   // idx 0..63
    const int m0 = (xcd * 8 + (idx & 7)) * 64;
    const int n0 = (idx >> 3) * 128;

    const int srow = lane >> 3;
    const int scolz = ((lane & 7) ^ srow) * 8;     // swizzled SOURCE col

    f32x4 acc[2][4];
#pragma unroll
    for (int i = 0; i < 2; i++)
#pragma unroll
        for (int j = 0; j < 4; j++)
#pragma unroll
            for (int r = 0; r < 4; r++) acc[i][j][r] = 0.f;

    for (int kt = 0; kt < K; kt += 64) {
        __syncthreads();
#pragma unroll
        for (int t = 0; t < 2; t++) {
            int rb = wave * 16 + t * 8;
            gl2lds16(A + (size_t)(m0 + rb + srow) * K + kt + scolz, &sA[rb * 64]);
        }
#pragma unroll
        for (int t = 0; t < 4; t++) {
            int rb = wave * 32 + t * 8;
            gl2lds16(Bt + (size_t)(n0 + rb + srow) * K + kt + scolz, &sB[rb * 64]);
        }
        __syncthreads();
#pragma unroll
        for (int kk = 0; kk < 64; kk += 32) {
            bf16x8 af[2], bfr[4];
            int sl = (((kk >> 3) + quad) ^ (l16 & 7)) * 8;   // swizzled slot
#pragma unroll
            for (int t = 0; t < 2; t++)
                af[t] = *(const bf16x8*)&sA[(wm + t * 16 + l16) * 64 + sl];
#pragma unroll
            for (int t = 0; t < 4; t++)
                bfr[t] = *(const bf16x8*)&sB[(wn + t * 16 + l16) * 64 + sl];
#pragma unroll
            for (int i = 0; i < 2; i++)
#pragma unroll
                for (int j = 0; j < 4; j++)
                    acc[i][j] = __builtin_amdgcn_mfma_f32_16x16x32_bf16(
                        af[i], bfr[j], acc[i][j], 0, 0, 0);
        }
    }

#pragma unroll
    for (int i = 0; i < 2; i++) {
#pragma unroll
        for (int j = 0; j < 4; j++) {
            int n = n0 + wn + j * 16 + l16;
            float bv = bias[n];
#pragma unroll
            for (int r = 0; r < 4; r++) {
                int m = m0 + wm + i * 16 + quad * 4 + r;
                out[(size_t)m * 1024 + n] = acc[i][j][r] + bv;
            }
        }
    }
}

// ---------------------------------------------------------------------------
extern "C" void kernel_launch(void* const* d_in, const int* in_sizes, int n_in,
                              void* d_out, int out_size, void* d_ws, size_t ws_size,
                              hipStream_t stream) {
    const float* x     = (const float*)d_in[0];
    const float* Wqkv  = (const float*)d_in[1];
    const float* bqkv  = (const float*)d_in[2];
    const float* Wproj = (const float*)d_in[3];
    const float* bproj = (const float*)d_in[4];
    float* out = (float*)d_out;
    char* ws = (char*)d_ws;

    u16* wqkvT  = (u16*)(ws);              // 6291456 B (dead after gemm_qkv)
    u16* wprojT = (u16*)(ws +  6291456);   // 2097152 B (live until gemm_proj)
    u16* xb     = (u16*)(ws +  8388608);   // 8388608 B (dead after gemm_qkv)
    u16* qb     = (u16*)(ws + 16777216);   // [B,H,N,D]
    u16* kb     = (u16*)(ws + 25165824);   // [B,H,N,D]
    u16* vtb    = (u16*)(ws + 33554432);   // [B,H,D,N]
    u16* ob     = (u16*)(ws + 41943040);   // [B,N,E]  (= op0, combined in place)

    // partial buffers reuse dead slots during attention:
    u16*   op0 = ob;                       // half-0 unnormalized O (bf16)
    u16*   op1 = xb;                       // half-1 unnormalized O (bf16)
    float* lp0 = (float*)wqkvT;            // 65536 floats = 256 KB
    float* lp1 = (float*)(ws + 262144);    // next 256 KB (still in wqkvT slot)

    prep_kernel<<<dim3(3072), 256, 0, stream>>>(x, xb, Wqkv, wqkvT, Wproj, wprojT);
    gemm_qkv<<<dim3(24, 32), 256, 0, stream>>>(xb, wqkvT, bqkv, qb, kb, vtb);
    attn_kernel<<<dim3(1024), 256, 0, stream>>>(qb, kb, vtb, op0, op1, lp0, lp1);
    combine_kernel<<<dim3(2048), 256, 0, stream>>>(op0, op1, lp0, lp1, ob);
    gemm_proj<<<dim3(512), 256, 0, stream>>>(ob, wprojT, bproj, out);
}

// Round 5
// 187.386 us; speedup vs baseline: 1.1348x; 1.0397x over previous
//
#include <hip/hip_runtime.h>
#include <hip/hip_bf16.h>
#include <stdint.h>

typedef unsigned short u16;
typedef __bf16 bf16x8 __attribute__((ext_vector_type(8)));
typedef float f32x4 __attribute__((ext_vector_type(4)));
typedef float f32x16 __attribute__((ext_vector_type(16)));

__device__ __forceinline__ u16 f2bf(float f) {
    union { float f; unsigned u; } x; x.f = f;
    unsigned u = x.u;
    u += 0x7FFFu + ((u >> 16) & 1u);   // round-to-nearest-even
    return (u16)(u >> 16);
}
__device__ __forceinline__ float bf2f(u16 h) {
    union { unsigned u; float f; } x; x.u = ((unsigned)h) << 16; return x.f;
}

// async global->LDS, 16B per lane; LDS dest is wave-uniform base + lane*16.
typedef __attribute__((address_space(1))) void gvoid;
typedef __attribute__((address_space(3))) void lvoid;
__device__ __forceinline__ void gl2lds16(const void* g, void* l) {
    __builtin_amdgcn_global_load_lds((gvoid*)g, (lvoid*)l, 16, 0, 0);
}

// ---------------------------------------------------------------------------
// Merged prep: blocks [0,2048): cast x -> bf16; [2048,2816): castT Wqkv;
// [2816,3072): castT Wproj.
// ---------------------------------------------------------------------------
__global__ __launch_bounds__(256) void prep_kernel(
    const float* __restrict__ x, u16* __restrict__ xb,
    const float* __restrict__ Wqkv, u16* __restrict__ wqkvT,
    const float* __restrict__ Wproj, u16* __restrict__ wprojT)
{
    __shared__ u16 tile[64][65];
    const int blk = blockIdx.x;
    const int tid = threadIdx.x;

    if (blk < 2048) {
        const size_t i = ((size_t)blk * 256 + tid) * 8;
        float4 a = *(const float4*)(x + i);
        float4 b = *(const float4*)(x + i + 4);
        ushort4 oa, ob;
        oa.x = f2bf(a.x); oa.y = f2bf(a.y); oa.z = f2bf(a.z); oa.w = f2bf(a.w);
        ob.x = f2bf(b.x); ob.y = f2bf(b.y); ob.z = f2bf(b.z); ob.w = f2bf(b.w);
        *(ushort4*)(xb + i) = oa;
        *(ushort4*)(xb + i + 4) = ob;
        return;
    }
    const float* in; u16* out; int rows, cols, bx, by;
    if (blk < 2816) { int t = blk - 2048; in = Wqkv;  out = wqkvT;  rows = 1024; cols = 3072; bx = t % 48; by = t / 48; }
    else            { int t = blk - 2816; in = Wproj; out = wprojT; rows = 1024; cols = 1024; bx = t % 16; by = t / 16; }
#pragma unroll
    for (int i = 0; i < 16; i++) {
        int e = i * 256 + tid;
        int r = e >> 6, c = e & 63;
        tile[r][c] = f2bf(in[(size_t)(by * 64 + r) * cols + bx * 64 + c]);
    }
    __syncthreads();
#pragma unroll
    for (int i = 0; i < 16; i++) {
        int e = i * 256 + tid;
        int r = e >> 6, c = e & 63;
        out[(size_t)(bx * 64 + r) * rows + by * 64 + c] = tile[c][r];
    }
}

// ---------------------------------------------------------------------------
// QKV GEMM v5 (frozen): gl2lds + T2 XOR-swizzle on sA/sB.
// ---------------------------------------------------------------------------
__global__ __launch_bounds__(256) void gemm_qkv(
    const u16* __restrict__ A, const u16* __restrict__ Bt,
    const float* __restrict__ bias,
    u16* __restrict__ q, u16* __restrict__ ko, u16* __restrict__ vt)
{
    constexpr int K = 1024;
    __shared__ __align__(16) u16 smem[128 * 132];
    u16* sA = smem;
    u16* sB = smem + 8192;
    const int tid = threadIdx.x;
    const int wave = tid >> 6, lane = tid & 63;
    const int quad = lane >> 4, l16 = lane & 15;
    const int wm = (wave >> 1) * 64, wn = (wave & 1) * 64;
    const int m0 = blockIdx.y * 128, n0 = blockIdx.x * 128;
    const int srow = lane >> 3;                    // 0..7
    const int scolz = ((lane & 7) ^ srow) * 8;     // swizzled SOURCE col

    f32x4 acc[4][4];
#pragma unroll
    for (int i = 0; i < 4; i++)
#pragma unroll
        for (int j = 0; j < 4; j++)
#pragma unroll
            for (int r = 0; r < 4; r++) acc[i][j][r] = 0.f;

    for (int kt = 0; kt < K; kt += 64) {
        __syncthreads();
#pragma unroll
        for (int t = 0; t < 4; t++) {
            int rb = wave * 32 + t * 8;
            gl2lds16(A  + (size_t)(m0 + rb + srow) * K + kt + scolz, &sA[rb * 64]);
            gl2lds16(Bt + (size_t)(n0 + rb + srow) * K + kt + scolz, &sB[rb * 64]);
        }
        __syncthreads();
#pragma unroll
        for (int kk = 0; kk < 64; kk += 32) {
            bf16x8 af[4], bfr[4];
#pragma unroll
            for (int t = 0; t < 4; t++) {
                int sl = (((kk >> 3) + quad) ^ (l16 & 7)) * 8;   // swizzled slot
                af[t]  = *(const bf16x8*)&sA[(wm + t * 16 + l16) * 64 + sl];
                bfr[t] = *(const bf16x8*)&sB[(wn + t * 16 + l16) * 64 + sl];
            }
#pragma unroll
            for (int i = 0; i < 4; i++)
#pragma unroll
                for (int j = 0; j < 4; j++)
                    acc[i][j] = __builtin_amdgcn_mfma_f32_16x16x32_bf16(
                        af[i], bfr[j], acc[i][j], 0, 0, 0);
        }
    }

    const float QSCALE = 0.18033688011112042f;  // 0.125 * log2(e)
    const float sc = (n0 < 1024) ? QSCALE : 1.0f;
    __syncthreads();
#pragma unroll
    for (int i = 0; i < 4; i++) {
#pragma unroll
        for (int j = 0; j < 4; j++) {
            float bv = bias[n0 + wn + j * 16 + l16];
#pragma unroll
            for (int r = 0; r < 4; r++) {
                float v = (acc[i][j][r] + bv) * sc;
                smem[(wm + i * 16 + quad * 4 + r) * 132 + wn + j * 16 + l16] = f2bf(v);
            }
        }
    }
    __syncthreads();

    if (n0 < 2048) {
        u16* dst = (n0 < 1024) ? q : ko;
#pragma unroll
        for (int it = 0; it < 8; it++) {
            int c = it * 256 + tid;
            int m_l = c >> 4;
            int n8 = (c & 15) * 8;
            uint4 w = *(const uint4*)&smem[m_l * 132 + n8];
            int n = n0 + n8;
            int h = (n & 1023) >> 6, d = n & 63;
            int m = m0 + m_l;
            int b = m >> 11, t = m & 2047;
            *(uint4*)(dst + ((size_t)(b * 16 + h) * 2048 + t) * 64 + d) = w;
        }
    } else {
        int nv = n0 - 2048;
        int n_l = tid & 127, mh = tid >> 7;
        int hh = (nv >> 6) + (n_l >> 6);
        int d = n_l & 63;
        int bb = m0 >> 11, t0 = m0 & 2047;
        u16* vrow = vt + ((size_t)(bb * 16 + hh) * 64 + d) * 2048 + t0 + mh * 64;
#pragma unroll
        for (int it = 0; it < 8; it++) {
            int tch = mh * 64 + it * 8;
            union { u16 s[8]; uint4 w; } pk;
#pragma unroll
            for (int i = 0; i < 8; i++)
                pk.s[i] = smem[(tch + i) * 132 + n_l];
            *(uint4*)(vrow + it * 8) = pk.w;
        }
    }
}

// ---------------------------------------------------------------------------
// Flash attention v11: v10 + VALU diet + single barrier per k-tile.
// - Pack: round-to-nearest via +0x8000, merge (r1&0xFFFF0000)|(r0>>16)
//   (compiler folds to v_perm_b32). 7 -> 3 ops/pair vs RNE. Ties differ
//   from RNE by 1 ulp, zero-mean -- same error profile as passing v10.
// - lsum: 4 partial accumulators (breaks 32-deep serial FP add chain).
// - Double-buffered sK/sV needs only ONE barrier per iteration: writes(t+1)
//   hit the opposite buffer of reads(t); writes(t+2) vs reads(t) are ordered
//   by bar(t+1). Trailing barrier removed (32 -> 16 barriers).
// LDS access patterns verified at their b128/b64 cycle floors; conflict
// counter (2^22 exactly) is structural residue -- not a lever.
// ---------------------------------------------------------------------------
__global__ __launch_bounds__(256, 4) void attn_kernel(
    const u16* __restrict__ q, const u16* __restrict__ ko,
    const u16* __restrict__ vt,
    u16* __restrict__ op0, u16* __restrict__ op1,
    float* __restrict__ lp0, float* __restrict__ lp1)
{
    __shared__ __align__(16) u16 sK[2][64 * 72];   // [n][d], pitch 72
    __shared__ __align__(16) u16 sV[2][64 * 72];   // [d][n], pitch 72

    const int tid = threadIdx.x;
    const int wave = tid >> 6, lane = tid & 63;
    const int l31 = lane & 31, hi = lane >> 5;

    const int lid = blockIdx.x;
    const int xcd = lid & 7, idx = lid >> 3;     // idx 0..127
    const int h = xcd * 2 + (idx & 1);
    const int b = (idx >> 1) & 1;
    const int q0 = ((idx >> 2) & 15) * 128;
    const int khalf = idx >> 6;                  // 0 or 1
    const int kbase = khalf * 1024;
    const size_t bh = (size_t)(b * 16 + h);

    const u16* qp  = q  + bh * 2048 * 64;
    const u16* kp  = ko + bh * 2048 * 64;
    const u16* vtp = vt + bh * 64 * 2048;

    // Q fragments straight from global: B-operand of 32x32x16.
    bf16x8 qf[4];
    {
        const u16* qrow = qp + (size_t)(q0 + wave * 32 + l31) * 64 + hi * 8;
#pragma unroll
        for (int d = 0; d < 4; d++)
            qf[d] = *(const bf16x8*)(qrow + d * 16);
    }

    const int sr0 = tid >> 3;          // 0..31
    const int sc0 = (tid & 7) * 8;
    const int sr1 = sr0 + 32;

    // prefetch tile 0 K/V of this half
    uint4 pk0 = *(const uint4*)(kp + (size_t)(kbase + sr0) * 64 + sc0);
    uint4 pk1 = *(const uint4*)(kp + (size_t)(kbase + sr1) * 64 + sc0);
    uint4 pv0 = *(const uint4*)(vtp + (size_t)sr0 * 2048 + kbase + sc0);
    uint4 pv1 = *(const uint4*)(vtp + (size_t)sr1 * 2048 + kbase + sc0);

    f32x16 accO[2];
#pragma unroll
    for (int d = 0; d < 2; d++)
#pragma unroll
        for (int r = 0; r < 16; r++) accO[d][r] = 0.f;
    float ls[4] = {0.f, 0.f, 0.f, 0.f};

    for (int t = 0; t < 16; ++t) {
        const int cur = t & 1;
        u16* sKc = &sK[cur][0];
        u16* sVc = &sV[cur][0];
        *(uint4*)&sKc[sr0 * 72 + sc0] = pk0;
        *(uint4*)&sKc[sr1 * 72 + sc0] = pk1;
        *(uint4*)&sVc[sr0 * 72 + sc0] = pv0;
        *(uint4*)&sVc[sr1 * 72 + sc0] = pv1;
        if (t < 15) {
            int nt = kbase + (t + 1) * 64;
            pk0 = *(const uint4*)(kp + (size_t)(nt + sr0) * 64 + sc0);
            pk1 = *(const uint4*)(kp + (size_t)(nt + sr1) * 64 + sc0);
            pv0 = *(const uint4*)(vtp + (size_t)sr0 * 2048 + nt + sc0);
            pv1 = *(const uint4*)(vtp + (size_t)sr1 * 2048 + nt + sc0);
        }
        __syncthreads();   // sole barrier: tile t staged; buffer cur^1 free

#pragma unroll
        for (int rb = 0; rb < 2; rb++) {
            // S^T block: D = mfma(A=K, B=Q), lane holds
            // S^T[krow = (r&3)+8*(r>>2)+4*hi][q = l31] (rows rb*32..+31)
            f32x16 S;
#pragma unroll
            for (int r = 0; r < 16; r++) S[r] = 0.f;
            const u16* krd = &sKc[(rb * 32 + l31) * 72 + hi * 8];
#pragma unroll
            for (int d = 0; d < 4; d++) {
                bf16x8 kf = *(const bf16x8*)(krd + d * 16);
                S = __builtin_amdgcn_mfma_f32_32x32x16_bf16(kf, qf[d], S, 0, 0, 0);
            }
            union { float f; unsigned u; } e[16];
#pragma unroll
            for (int r = 0; r < 16; r++) {
                e[r].f = __builtin_amdgcn_exp2f(S[r]);
                ls[r & 3] += e[r].f;
            }
            // O += P @ V. A slot (hi,j) <- P[krow f], B slot (hi,j) <- V[row f],
            // f = rb*32 + ks2*16 + 4*hi + (j&3) + 8*(j>>2).
#pragma unroll
            for (int ks2 = 0; ks2 < 2; ks2++) {
                union { unsigned u[4]; bf16x8 v; } pa;
#pragma unroll
                for (int s = 0; s < 4; s++) {
                    unsigned r0 = e[ks2 * 8 + 2 * s].u + 0x8000u;      // RN
                    unsigned r1 = e[ks2 * 8 + 2 * s + 1].u + 0x8000u;  // RN
                    pa.u[s] = (r1 & 0xFFFF0000u) | (r0 >> 16);
                }
                const int nb = rb * 32 + ks2 * 16 + 4 * hi;
#pragma unroll
                for (int db = 0; db < 2; db++) {
                    const u16* vr = &sVc[(db * 32 + l31) * 72 + nb];
                    union { uint2 w[2]; bf16x8 v; } vf;
                    vf.w[0] = *(const uint2*)(vr);
                    vf.w[1] = *(const uint2*)(vr + 8);
                    accO[db] = __builtin_amdgcn_mfma_f32_32x32x16_bf16(pa.v, vf.v, accO[db], 0, 0, 0);
                }
            }
        }
    }

    // epilogue: write unnormalized O (bf16) + l (fp32) for this half
    u16* op = khalf ? op1 : op0;
    float* lp = khalf ? lp1 : lp0;

    float lsum = (ls[0] + ls[1]) + (ls[2] + ls[3]);
    float ltot = lsum + __shfl_xor(lsum, 32, 64);
    int qq0 = q0 + wave * 32;
    if (hi == 0) lp[bh * 2048 + qq0 + l31] = ltot;

#pragma unroll
    for (int db = 0; db < 2; db++)
#pragma unroll
        for (int r = 0; r < 16; r++) {
            int tq = qq0 + (r & 3) + 8 * (r >> 2) + 4 * hi;
            size_t row = (size_t)b * 2048 + tq;
            op[row * 1024 + h * 64 + db * 32 + l31] = f2bf(accO[db][r]);
        }
}

// ---------------------------------------------------------------------------
// Combine: ob = (O0 + O1) / (l0 + l1); ob aliases op0 (same-element RMW safe).
// ---------------------------------------------------------------------------
__global__ __launch_bounds__(256) void combine_kernel(
    const u16* __restrict__ op0, const u16* __restrict__ op1,
    const float* __restrict__ lp0, const float* __restrict__ lp1,
    u16* __restrict__ ob)
{
    const size_t i = ((size_t)blockIdx.x * 256 + threadIdx.x) * 8;
    int m = (int)(i >> 10), e = (int)(i & 1023);
    int b = m >> 11, t = m & 2047, h = e >> 6;
    float inv = 1.f / (lp0[(size_t)(b * 16 + h) * 2048 + t] +
                       lp1[(size_t)(b * 16 + h) * 2048 + t]);
    union { uint4 w; u16 s[8]; } a, c, o;
    a.w = *(const uint4*)(op0 + i);
    c.w = *(const uint4*)(op1 + i);
#pragma unroll
    for (int k = 0; k < 8; k++)
        o.s[k] = f2bf((bf2f(a.s[k]) + bf2f(c.s[k])) * inv);
    *(uint4*)(ob + i) = o.w;
}

// ---------------------------------------------------------------------------
// Proj GEMM v5 (frozen): T2 XOR-swizzle, 64m x 128n tiles, grid 512.
// ---------------------------------------------------------------------------
__global__ __launch_bounds__(256) void gemm_proj(
    const u16* __restrict__ A, const u16* __restrict__ Bt,
    const float* __restrict__ bias, float* __restrict__ out)
{
    constexpr int K = 1024;
    __shared__ __align__(16) u16 sA[64 * 64];
    __shared__ __align__(16) u16 sB[128 * 64];
    const int tid = threadIdx.x;
    const int wave = tid >> 6, lane = tid & 63;
    const int quad = lane >> 4, l16 = lane & 15;
    const int wm = (wave & 1) * 32, wn = (wave >> 1) * 64;

    const int lid = blockIdx.x;
    const int xcd = lid & 7, idx = lid >> 3;   // idx 0..63
    const int m0 = (xcd * 8 + (idx & 7)) * 64;
    const int n0 = (idx >> 3) * 128;

    const int srow = lane >> 3;
    const int scolz = ((lane & 7) ^ srow) * 8;     // swizzled SOURCE col

    f32x4 acc[2][4];
#pragma unroll
    for (int i = 0; i < 2; i++)
#pragma unroll
        for (int j = 0; j < 4; j++)
#pragma unroll
            for (int r = 0; r < 4; r++) acc[i][j][r] = 0.f;

    for (int kt = 0; kt < K; kt += 64) {
        __syncthreads();
#pragma unroll
        for (int t = 0; t < 2; t++) {
            int rb = wave * 16 + t * 8;
            gl2lds16(A + (size_t)(m0 + rb + srow) * K + kt + scolz, &sA[rb * 64]);
        }
#pragma unroll
        for (int t = 0; t < 4; t++) {
            int rb = wave * 32 + t * 8;
            gl2lds16(Bt + (size_t)(n0 + rb + srow) * K + kt + scolz, &sB[rb * 64]);
        }
        __syncthreads();
#pragma unroll
        for (int kk = 0; kk < 64; kk += 32) {
            bf16x8 af[2], bfr[4];
            int sl = (((kk >> 3) + quad) ^ (l16 & 7)) * 8;   // swizzled slot
#pragma unroll
            for (int t = 0; t < 2; t++)
                af[t] = *(const bf16x8*)&sA[(wm + t * 16 + l16) * 64 + sl];
#pragma unroll
            for (int t = 0; t < 4; t++)
                bfr[t] = *(const bf16x8*)&sB[(wn + t * 16 + l16) * 64 + sl];
#pragma unroll
            for (int i = 0; i < 2; i++)
#pragma unroll
                for (int j = 0; j < 4; j++)
                    acc[i][j] = __builtin_amdgcn_mfma_f32_16x16x32_bf16(
                        af[i], bfr[j], acc[i][j], 0, 0, 0);
        }
    }

#pragma unroll
    for (int i = 0; i < 2; i++) {
#pragma unroll
        for (int j = 0; j < 4; j++) {
            int n = n0 + wn + j * 16 + l16;
            float bv = bias[n];
#pragma unroll
            for (int r = 0; r < 4; r++) {
                int m = m0 + wm + i * 16 + quad * 4 + r;
                out[(size_t)m * 1024 + n] = acc[i][j][r] + bv;
            }
        }
    }
}

// ---------------------------------------------------------------------------
extern "C" void kernel_launch(void* const* d_in, const int* in_sizes, int n_in,
                              void* d_out, int out_size, void* d_ws, size_t ws_size,
                              hipStream_t stream) {
    const float* x     = (const float*)d_in[0];
    const float* Wqkv  = (const float*)d_in[1];
    const float* bqkv  = (const float*)d_in[2];
    const float* Wproj = (const float*)d_in[3];
    const float* bproj = (const float*)d_in[4];
    float* out = (float*)d_out;
    char* ws = (char*)d_ws;

    u16* wqkvT  = (u16*)(ws);              // 6291456 B (dead after gemm_qkv)
    u16* wprojT = (u16*)(ws +  6291456);   // 2097152 B (live until gemm_proj)
    u16* xb     = (u16*)(ws +  8388608);   // 8388608 B (dead after gemm_qkv)
    u16* qb     = (u16*)(ws + 16777216);   // [B,H,N,D]
    u16* kb     = (u16*)(ws + 25165824);   // [B,H,N,D]
    u16* vtb    = (u16*)(ws + 33554432);   // [B,H,D,N]
    u16* ob     = (u16*)(ws + 41943040);   // [B,N,E]  (= op0, combined in place)

    // partial buffers reuse dead slots during attention:
    u16*   op0 = ob;                       // half-0 unnormalized O (bf16)
    u16*   op1 = xb;                       // half-1 unnormalized O (bf16)
    float* lp0 = (float*)wqkvT;            // 65536 floats = 256 KB
    float* lp1 = (float*)(ws + 262144);    // next 256 KB (still in wqkvT slot)

    prep_kernel<<<dim3(3072), 256, 0, stream>>>(x, xb, Wqkv, wqkvT, Wproj, wprojT);
    gemm_qkv<<<dim3(24, 32), 256, 0, stream>>>(xb, wqkvT, bqkv, qb, kb, vtb);
    attn_kernel<<<dim3(1024), 256, 0, stream>>>(qb, kb, vtb, op0, op1, lp0, lp1);
    combine_kernel<<<dim3(2048), 256, 0, stream>>>(op0, op1, lp0, lp1, ob);
    gemm_proj<<<dim3(512), 256, 0, stream>>>(ob, wprojT, bproj, out);
}